// Round 3
// baseline (324.858 us; speedup 1.0000x reference)
//
#include <hip/hip_runtime.h>

// Colorcal: out[b,c,h,w] = image[b,c,h,w] * weight[cam[b],c] + bias[cam[b],c]
// image: [16,3,1024,1024] fp32. Memory-bound: 402.7 MB mandatory traffic
// (201.3 MB read + 201.3 MB write). Roofline: 64 us at the 6.29 TB/s m13
// float4-copy ceiling; harness fills sustain 6.5-6.6 TB/s pure-write.
//
// R3 = R0 structure (best measured, 318.6 us total) with ONE variable
// changed: nontemporal hints removed. Rationale: within a single pass there
// is zero reuse (nt protects nothing), and the 768 MiB poison fill sweeps
// L3 between iterations (so cross-pass residency is dead regardless).
// Plain stores let up to ~200 MB of dirty output lines be absorbed by the
// 256 MiB L3 (output is 201 MB), deferring writeback past kernel end;
// plain accesses are also the exact pattern of the two fast references on
// this box (rocclr fill 6.6 TB/s, m13 copy 6.29 TB/s). R2's 8-f4/thread
// MLP restructure was neutral-to-negative (+5 us) -> BW-saturated regime,
// so we keep R0's maximally simple 1-f4/thread shape.
//
// Each (b,c) plane = 1024*1024 floats = 2^18 float4 = 1024 blocks of 256.

typedef float f4 __attribute__((ext_vector_type(4)));

__global__ __launch_bounds__(256) void colorcal_kernel(
    const f4*    __restrict__ img,
    const int*   __restrict__ cam_idx,
    const float* __restrict__ weight,
    const float* __restrict__ bias,
    f4*          __restrict__ out)
{
    // Wave-uniform scalar arithmetic (blockIdx lives in SGPRs):
    const int plane = blockIdx.x >> 10;       // 0..47  (b*3 + c)
    const int b     = plane / 3;
    const int c     = plane - b * 3;
    const int cam   = cam_idx[b];             // s_load (block-uniform)
    const float s   = weight[cam * 3 + c];    // s_load
    const float t   = bias[cam * 3 + c];      // s_load

    const int i = blockIdx.x * 256 + threadIdx.x;   // float4 index, < 12.6M

    f4 v = img[i];                            // plain global_load_dwordx4
    v.x = fmaf(v.x, s, t);
    v.y = fmaf(v.y, s, t);
    v.z = fmaf(v.z, s, t);
    v.w = fmaf(v.w, s, t);
    out[i] = v;                               // plain global_store_dwordx4
}

extern "C" void kernel_launch(void* const* d_in, const int* in_sizes, int n_in,
                              void* d_out, int out_size, void* d_ws, size_t ws_size,
                              hipStream_t stream)
{
    const f4*    img     = (const f4*)d_in[0];
    const int*   cam_idx = (const int*)d_in[1];
    const float* weight  = (const float*)d_in[2];
    const float* bias    = (const float*)d_in[3];
    f4*          out     = (f4*)d_out;

    const int n_f4  = out_size / 4;                  // 12,582,912
    const int block = 256;
    const int grid  = n_f4 / block;                  // 49,152 blocks (exact)
    colorcal_kernel<<<grid, block, 0, stream>>>(img, cam_idx, weight, bias, out);
}